// Round 1
// baseline (2700.748 us; speedup 1.0000x reference)
//
#include <hip/hip_runtime.h>

#define WS    8
#define SHIFT 4
#define HH    256
#define WWID  256
#define DD    96
#define NH    6
#define DK    16
#define WS2   64   // window_size^2
#define NTHR  384  // 6 waves = 6 heads

// region id along one axis for the Swin shift mask:
// rows 0..247 -> 0, 248..251 -> 1, 252..255 -> 2
__device__ __forceinline__ int region1d(int h) {
    return (h >= HH - SHIFT) ? 2 : ((h >= HH - WS) ? 1 : 0);
}

__global__ __launch_bounds__(NTHR)
void swin_attn_fused(const float* __restrict__ x,
                     const float* __restrict__ w_qkv,
                     const float* __restrict__ b_qkv,
                     const float* __restrict__ w_out,
                     const float* __restrict__ b_out,
                     const float* __restrict__ rpe_table,
                     float* __restrict__ out)
{
    // qs: q, later reused as per-window attention output (per-wave stripe ownership)
    __shared__ float qs[WS2][DD];
    __shared__ float ks[WS2][DD];
    __shared__ float vs[WS2][DD];   // x staging first, then v

    const int blk = blockIdx.x;
    const int b   = blk >> 10;        // / (32*32)
    const int wi  = (blk >> 5) & 31;
    const int wj  = blk & 31;

    const int tid = threadIdx.x;
    const int p   = tid & 63;         // window position = qr*8+qc
    const int hg  = tid >> 6;         // head (= wave id)

    // ---- Phase 0: stage the 64 x rows (shifted gather) into vs ----
    for (int idx = tid; idx < WS2 * DD; idx += NTHR) {
        int pp = idx / DD;
        int kk = idx - pp * DD;
        int r = pp >> 3, c = pp & 7;
        int gh = (wi * WS + r + SHIFT) & (HH - 1);
        int gw = (wj * WS + c + SHIFT) & (WWID - 1);
        size_t row = ((size_t)b * HH + gh) * WWID + gw;
        vs[pp][kk] = x[row * DD + kk];
    }
    __syncthreads();

    // ---- Phase 1: qkv projection. Thread (p, hg) computes its 3x16 stripe ----
    float accq[DK], acck[DK], accv[DK];
    #pragma unroll
    for (int d = 0; d < DK; ++d) {
        accq[d] = b_qkv[hg * DK + d];
        acck[d] = b_qkv[DD + hg * DK + d];
        accv[d] = b_qkv[2 * DD + hg * DK + d];
    }
    for (int k = 0; k < DD; ++k) {
        float xv = vs[p][k];
        const float* wr = w_qkv + (size_t)k * (3 * DD) + hg * DK;
        #pragma unroll
        for (int d = 0; d < DK; ++d) accq[d] += xv * wr[d];
        #pragma unroll
        for (int d = 0; d < DK; ++d) acck[d] += xv * wr[DD + d];
        #pragma unroll
        for (int d = 0; d < DK; ++d) accv[d] += xv * wr[2 * DD + d];
    }
    #pragma unroll
    for (int d = 0; d < DK; ++d) {
        qs[p][hg * DK + d] = accq[d];
        ks[p][hg * DK + d] = acck[d];
    }
    __syncthreads();                    // all x reads from vs done
    #pragma unroll
    for (int d = 0; d < DK; ++d) vs[p][hg * DK + d] = accv[d];
    __syncthreads();

    // ---- Phase 2: attention. Wave hg = head hg, lane p = query row ----
    float qreg[DK];
    #pragma unroll
    for (int d = 0; d < DK; ++d) qreg[d] = qs[p][hg * DK + d];

    const int qr = p >> 3, qc = p & 7;
    const int reg_q = region1d(wi * WS + qr) * 3 + region1d(wj * WS + qc);

    float sc[WS2];
    float mx = -3.0e38f;
    #pragma unroll
    for (int kp = 0; kp < WS2; ++kp) {
        float s = 0.f;
        #pragma unroll
        for (int d = 0; d < DK; ++d) s += qreg[d] * ks[kp][hg * DK + d];
        s *= 0.25f;                      // 1/sqrt(16)
        int kr = kp >> 3, kc = kp & 7;
        int ridx = (qr - kr + 7) * 15 + (qc - kc + 7);
        s += rpe_table[ridx * NH + hg];
        int reg_k = region1d(wi * WS + kr) * 3 + region1d(wj * WS + kc);
        if (reg_k != reg_q) s = -1e9f;
        sc[kp] = s;
        mx = fmaxf(mx, s);
    }
    float ssum = 0.f;
    #pragma unroll
    for (int kp = 0; kp < WS2; ++kp) {
        float e = __expf(sc[kp] - mx);
        sc[kp] = e;
        ssum += e;
    }
    const float rinv = 1.0f / ssum;

    float o[DK];
    #pragma unroll
    for (int d = 0; d < DK; ++d) o[d] = 0.f;
    #pragma unroll
    for (int kp = 0; kp < WS2; ++kp) {
        float a = sc[kp] * rinv;
        #pragma unroll
        for (int d = 0; d < DK; ++d) o[d] += a * vs[kp][hg * DK + d];
    }
    // attention output into qs — each wave touches only its own 16-col stripe
    #pragma unroll
    for (int d = 0; d < DK; ++d) qs[p][hg * DK + d] = o[d];
    __syncthreads();

    // ---- Phase 3: output projection. Thread (p, hg) -> out cols hg*16.. ----
    float acc[DK];
    #pragma unroll
    for (int d = 0; d < DK; ++d) acc[d] = b_out[hg * DK + d];
    for (int k = 0; k < DD; ++k) {
        float a = qs[p][k];
        const float* wr = w_out + (size_t)k * DD + hg * DK;
        #pragma unroll
        for (int d = 0; d < DK; ++d) acc[d] += a * wr[d];
    }
    {
        int gh = (wi * WS + qr + SHIFT) & (HH - 1);
        int gw = (wj * WS + qc + SHIFT) & (WWID - 1);
        size_t row = ((size_t)b * HH + gh) * WWID + gw;
        float* orow = out + row * DD + hg * DK;
        #pragma unroll
        for (int d = 0; d < DK; ++d) orow[d] = acc[d];
    }
}

extern "C" void kernel_launch(void* const* d_in, const int* in_sizes, int n_in,
                              void* d_out, int out_size, void* d_ws, size_t ws_size,
                              hipStream_t stream) {
    const float* x    = (const float*)d_in[0];
    const float* wqkv = (const float*)d_in[1];
    const float* bqkv = (const float*)d_in[2];
    const float* wout = (const float*)d_in[3];
    const float* bout = (const float*)d_in[4];
    const float* rpe  = (const float*)d_in[5];
    // d_in[6] (rp_index) and d_in[7] (mask) are recomputed in-kernel.
    float* out = (float*)d_out;

    const int B = in_sizes[0] / (HH * WWID * DD);
    dim3 grid(B * 32 * 32);
    dim3 block(NTHR);
    hipLaunchKernelGGL(swin_attn_fused, grid, block, 0, stream,
                       x, wqkv, bqkv, wout, bout, rpe, out);
}